// Round 3
// baseline (297.966 us; speedup 1.0000x reference)
//
#include <hip/hip_runtime.h>

typedef unsigned short u16;
typedef __bf16 bf16x8 __attribute__((ext_vector_type(8)));
typedef float f32x4 __attribute__((ext_vector_type(4)));

#define DD 1024
#define SS 2048
#define HH 16
#define HDIM 64

__device__ __forceinline__ u16 f2bf(float f) {
  union { float f; unsigned u; } x; x.f = f;
  unsigned r = x.u + 0x7FFFu + ((x.u >> 16) & 1u);
  return (u16)(r >> 16);
}

__device__ __forceinline__ void gload_lds16(const u16* g, u16* l) {
  __builtin_amdgcn_global_load_lds((const __attribute__((address_space(1))) void*)g,
                                   (__attribute__((address_space(3))) void*)l, 16, 0, 0);
}

// ---------------- fp32 -> bf16 convert ----------------
__global__ __launch_bounds__(256) void cvt_x(const float* __restrict__ in, u16* __restrict__ out, int n) {
  int i = (blockIdx.x * 256 + threadIdx.x) * 4;
  if (i + 3 < n) {
    float4 v = *(const float4*)(in + i);
    out[i + 0] = f2bf(v.x);
    out[i + 1] = f2bf(v.y);
    out[i + 2] = f2bf(v.z);
    out[i + 3] = f2bf(v.w);
  }
}

// ---------------- weight transpose + convert: out[n][k] = w[k][n] ----------------
__global__ __launch_bounds__(256) void transpose_w(const float* __restrict__ w0, const float* __restrict__ w1,
                                                   const float* __restrict__ w2, const float* __restrict__ w3,
                                                   u16* __restrict__ out) {
  __shared__ float t[32][33];
  const float* w = (blockIdx.z == 0) ? w0 : (blockIdx.z == 1) ? w1 : (blockIdx.z == 2) ? w2 : w3;
  u16* o = out + (size_t)blockIdx.z * DD * DD;
  int j0 = blockIdx.x * 32;  // n
  int i0 = blockIdx.y * 32;  // k
  int tx = threadIdx.x, ty = threadIdx.y;
#pragma unroll
  for (int r = ty; r < 32; r += 8)
    t[r][tx] = w[(size_t)(i0 + r) * DD + j0 + tx];
  __syncthreads();
#pragma unroll
  for (int r = ty; r < 32; r += 8)
    o[(size_t)(j0 + r) * DD + i0 + tx] = f2bf(t[tx][r]);
}

// ---------------- shared 128x128 GEMM core (A[M][K] bf16, BT[N][K] bf16) ----------------
__device__ __forceinline__ void gemm_128(const u16* __restrict__ A, const u16* __restrict__ BT,
                                         int m0, int n0, int K, u16* As, u16* Bs, f32x4 acc[4][4]) {
  const int tid = threadIdx.x;
  const int lane = tid & 63;
  const int wid = tid >> 6;
  const int wm = wid >> 1, wn = wid & 1;
  const int lr = lane & 15;
  const int lg = lane >> 4;
#pragma unroll
  for (int i = 0; i < 4; ++i)
#pragma unroll
    for (int j = 0; j < 4; ++j)
      acc[i][j] = (f32x4){0.f, 0.f, 0.f, 0.f};

  for (int kt = 0; kt < K / 64; ++kt) {
    int k0 = kt * 64;
    __syncthreads();
#pragma unroll
    for (int i = 0; i < 4; ++i) {
      int c = i * 256 + tid;
      int row = c >> 3;
      int j = (c & 7) ^ (row & 7);
      gload_lds16(A + (size_t)(m0 + row) * K + k0 + j * 8, As + c * 8);
      gload_lds16(BT + (size_t)(n0 + row) * K + k0 + j * 8, Bs + c * 8);
    }
    __syncthreads();
#pragma unroll
    for (int ks = 0; ks < 2; ++ks) {
      bf16x8 af[4], bfr[4];
#pragma unroll
      for (int mi = 0; mi < 4; ++mi) {
        int row = wm * 64 + mi * 16 + lr;
        int ch = (ks * 4 + lg) ^ (row & 7);
        af[mi] = *(const bf16x8*)(As + row * 64 + ch * 8);
      }
#pragma unroll
      for (int ni = 0; ni < 4; ++ni) {
        int row = wn * 64 + ni * 16 + lr;
        int ch = (ks * 4 + lg) ^ (row & 7);
        bfr[ni] = *(const bf16x8*)(Bs + row * 64 + ch * 8);
      }
      __builtin_amdgcn_s_setprio(1);
#pragma unroll
      for (int mi = 0; mi < 4; ++mi)
#pragma unroll
        for (int ni = 0; ni < 4; ++ni)
          acc[mi][ni] = __builtin_amdgcn_mfma_f32_16x16x32_bf16(af[mi], bfr[ni], acc[mi][ni], 0, 0, 0);
      __builtin_amdgcn_s_setprio(0);
    }
  }
}

// ---------------- QKV projection + RoPE epilogue ----------------
__global__ __launch_bounds__(256, 2) void gemm_qkv(const u16* __restrict__ xb, const u16* __restrict__ wT,
                                                   const float* __restrict__ fc, const float* __restrict__ fs,
                                                   u16* __restrict__ Qr, u16* __restrict__ Kr, u16* __restrict__ Vt) {
  __shared__ u16 As[128 * 64], Bs[128 * 64];
  const int z = blockIdx.z;
  const u16* BT = wT + (size_t)z * DD * DD;
  f32x4 acc[4][4];
  int m0 = blockIdx.x * 128, n0 = blockIdx.y * 128;
  gemm_128(xb, BT, m0, n0, DD, As, Bs, acc);

  const int lane = threadIdx.x & 63, wid = threadIdx.x >> 6;
  const int wm = wid >> 1, wn = wid & 1, lr = lane & 15, lg = lane >> 4;
#pragma unroll
  for (int mi = 0; mi < 4; ++mi)
#pragma unroll
    for (int ni = 0; ni < 4; ++ni)
#pragma unroll
      for (int j = 0; j < 4; ++j) {
        int m = m0 + wm * 64 + mi * 16 + lg * 4 + j;
        int n = n0 + wn * 64 + ni * 16 + lr;
        float v = acc[mi][ni][j];
        int b = m >> 11, s = m & 2047;
        int h = n >> 6, hd = n & 63;
        if (z == 2) {
          Vt[((size_t)(b * HH + h) * HDIM + hd) * SS + s] = f2bf(v);
        } else {
          float pv = __shfl_xor(v, 1);
          int fi = s * 32 + (hd >> 1);
          float c = fc[fi], sn = fs[fi];
          float o = ((hd & 1) == 0) ? (v * c - pv * sn) : (pv * sn + v * c);
          u16* dst = (z == 0) ? Qr : Kr;
          dst[((size_t)(b * HH + h) * SS + s) * HDIM + hd] = f2bf(o);
        }
      }
}

// ---------------- flash attention (causal), one 64-row q-tile pass, KVBLK=128 ----------------
__device__ __forceinline__ void attn_pass(int qt, int bh, const u16* __restrict__ Qh,
                                          const u16* __restrict__ Kh, const u16* __restrict__ Vh,
                                          u16* __restrict__ Ob, u16* __restrict__ Pw) {
  const int lane = threadIdx.x & 63, wid = threadIdx.x >> 6;
  const int lr = lane & 15, lg = lane >> 4;
  const int q0 = qt * 64 + wid * 16;

  bf16x8 aq[2];
#pragma unroll
  for (int ks = 0; ks < 2; ++ks)
    aq[ks] = *(const bf16x8*)(Qh + (q0 + lr) * HDIM + ks * 32 + lg * 8);

  f32x4 o[4];
#pragma unroll
  for (int d = 0; d < 4; ++d) o[d] = (f32x4){0.f, 0.f, 0.f, 0.f};
  float mrun[4], lrun[4];
#pragma unroll
  for (int j = 0; j < 4; ++j) { mrun[j] = -1e30f; lrun[j] = 0.f; }

  const int nb = (qt + 2) >> 1;  // number of 128-wide K/V blocks

  // preload K for block 0 (sub-tiles 0,1)
  bf16x8 kf[2][2][4];  // [tt][ks][kb]
#pragma unroll
  for (int tt = 0; tt < 2; ++tt)
#pragma unroll
    for (int ks = 0; ks < 2; ++ks)
#pragma unroll
      for (int kb = 0; kb < 4; ++kb)
        kf[tt][ks][kb] = *(const bf16x8*)(Kh + (tt * 64 + kb * 16 + lr) * HDIM + ks * 32 + lg * 8);

  for (int i = 0; i < nb; ++i) {
    const int tb = i * 128;
    // V fragments for this block: issue FIRST (latency hides under QK^T + softmax)
    bf16x8 vf[2][2][4];  // [tt][ks][d]
#pragma unroll
    for (int tt = 0; tt < 2; ++tt)
#pragma unroll
      for (int ks = 0; ks < 2; ++ks)
#pragma unroll
        for (int d = 0; d < 4; ++d)
          vf[tt][ks][d] = *(const bf16x8*)(Vh + (d * 16 + lr) * SS + tb + tt * 64 + ks * 32 + lg * 8);

    f32x4 sc[2][4];
#pragma unroll
    for (int tt = 0; tt < 2; ++tt)
#pragma unroll
      for (int kb = 0; kb < 4; ++kb) sc[tt][kb] = (f32x4){0.f, 0.f, 0.f, 0.f};
    __builtin_amdgcn_s_setprio(1);
#pragma unroll
    for (int tt = 0; tt < 2; ++tt)
#pragma unroll
      for (int ks = 0; ks < 2; ++ks)
#pragma unroll
        for (int kb = 0; kb < 4; ++kb)
          sc[tt][kb] = __builtin_amdgcn_mfma_f32_16x16x32_bf16(aq[ks], kf[tt][ks][kb], sc[tt][kb], 0, 0, 0);
    __builtin_amdgcn_s_setprio(0);

    // prefetch next block's K into kf (WAR after QK^T; latency hides under softmax+PV)
    const int ip = (i + 1 < nb) ? (i + 1) : i;
#pragma unroll
    for (int tt = 0; tt < 2; ++tt)
#pragma unroll
      for (int ks = 0; ks < 2; ++ks)
#pragma unroll
        for (int kb = 0; kb < 4; ++kb)
          kf[tt][ks][kb] = *(const bf16x8*)(Kh + (ip * 128 + tt * 64 + kb * 16 + lr) * HDIM + ks * 32 + lg * 8);

    // scale + mask (only final block has masked columns); softmax over 128 cols
    float pm[4] = {-1e30f, -1e30f, -1e30f, -1e30f};
    if (i == nb - 1) {
#pragma unroll
      for (int tt = 0; tt < 2; ++tt)
#pragma unroll
        for (int kb = 0; kb < 4; ++kb)
#pragma unroll
          for (int j = 0; j < 4; ++j) {
            int q = q0 + lg * 4 + j;
            int kk = tb + tt * 64 + kb * 16 + lr;
            float v = sc[tt][kb][j] * 0.125f;
            if (kk > q) v = -1e30f;
            sc[tt][kb][j] = v;
            pm[j] = fmaxf(pm[j], v);
          }
    } else {
#pragma unroll
      for (int tt = 0; tt < 2; ++tt)
#pragma unroll
        for (int kb = 0; kb < 4; ++kb)
#pragma unroll
          for (int j = 0; j < 4; ++j) {
            float v = sc[tt][kb][j] * 0.125f;
            sc[tt][kb][j] = v;
            pm[j] = fmaxf(pm[j], v);
          }
    }
#pragma unroll
    for (int d = 1; d < 16; d <<= 1)
#pragma unroll
      for (int j = 0; j < 4; ++j) pm[j] = fmaxf(pm[j], __shfl_xor(pm[j], d));
    float alpha[4], psum[4];
#pragma unroll
    for (int j = 0; j < 4; ++j) {
      float mn = fmaxf(mrun[j], pm[j]);
      alpha[j] = __expf(mrun[j] - mn);
      mrun[j] = mn;
      psum[j] = 0.f;
    }
#pragma unroll
    for (int tt = 0; tt < 2; ++tt)
#pragma unroll
      for (int kb = 0; kb < 4; ++kb)
#pragma unroll
        for (int j = 0; j < 4; ++j) {
          float e = __expf(sc[tt][kb][j] - mrun[j]);
          sc[tt][kb][j] = e;
          psum[j] += e;
        }
#pragma unroll
    for (int d = 1; d < 16; d <<= 1)
#pragma unroll
      for (int j = 0; j < 4; ++j) psum[j] += __shfl_xor(psum[j], d);
#pragma unroll
    for (int j = 0; j < 4; ++j) lrun[j] = lrun[j] * alpha[j] + psum[j];
#pragma unroll
    for (int d = 0; d < 4; ++d)
#pragma unroll
      for (int j = 0; j < 4; ++j) o[d][j] *= alpha[j];

    // P -> per-wave LDS (swizzled, 16 rows x 128 cols), then PV
#pragma unroll
    for (int tt = 0; tt < 2; ++tt)
#pragma unroll
      for (int kb = 0; kb < 4; ++kb)
#pragma unroll
        for (int j = 0; j < 4; ++j) {
          int r = lg * 4 + j;
          int chl = tt * 8 + kb * 2 + (lr >> 3);
          int ch = chl ^ (r & 7);
          Pw[r * 128 + ch * 8 + (lr & 7)] = f2bf(sc[tt][kb][j]);
        }
#pragma unroll
    for (int tt = 0; tt < 2; ++tt)
#pragma unroll
      for (int ks = 0; ks < 2; ++ks) {
        int ch = (tt * 8 + ks * 4 + lg) ^ (lr & 7);
        bf16x8 ap = *(const bf16x8*)(Pw + lr * 128 + ch * 8);
        __builtin_amdgcn_s_setprio(1);
#pragma unroll
        for (int d = 0; d < 4; ++d)
          o[d] = __builtin_amdgcn_mfma_f32_16x16x32_bf16(ap, vf[tt][ks][d], o[d], 0, 0, 0);
        __builtin_amdgcn_s_setprio(0);
      }
  }
  const int b = bh >> 4, h = bh & 15;
#pragma unroll
  for (int d = 0; d < 4; ++d)
#pragma unroll
    for (int j = 0; j < 4; ++j) {
      int s = q0 + lg * 4 + j;
      int col = h * HDIM + d * 16 + lr;
      Ob[((size_t)b * SS + s) * DD + col] = f2bf(o[d][j] / lrun[j]);
    }
}

// 512 flat blocks; XCD-aware mapping: xcd = id&7 owns heads 4*xcd..4*xcd+3 (K/V L2-resident).
__global__ __launch_bounds__(256, 2) void attn(const u16* __restrict__ Qr, const u16* __restrict__ Kr,
                                               const u16* __restrict__ Vt, u16* __restrict__ Ob) {
  __shared__ u16 Ps[4][16 * 128];
  const int id = blockIdx.x;
  const int xcd = id & 7;
  const int idx = id >> 3;
  const int pair = idx & 15;
  const int bh = xcd * 4 + (idx >> 4);
  const u16* Qh = Qr + (size_t)bh * SS * HDIM;
  const u16* Kh = Kr + (size_t)bh * SS * HDIM;
  const u16* Vh = Vt + (size_t)bh * HDIM * SS;
  u16* Pw = &Ps[threadIdx.x >> 6][0];
  attn_pass(pair, bh, Qh, Kh, Vh, Ob, Pw);
  attn_pass(31 - pair, bh, Qh, Kh, Vh, Ob, Pw);
}

// ---------------- output projection: fp32 out ----------------
__global__ __launch_bounds__(256, 2) void gemm_wo(const u16* __restrict__ Ab, const u16* __restrict__ woT,
                                                  float* __restrict__ out) {
  __shared__ u16 As[128 * 64], Bs[128 * 64];
  f32x4 acc[4][4];
  int m0 = blockIdx.x * 128, n0 = blockIdx.y * 128;
  gemm_128(Ab, woT, m0, n0, DD, As, Bs, acc);
  const int lane = threadIdx.x & 63, wid = threadIdx.x >> 6;
  const int wm = wid >> 1, wn = wid & 1, lr = lane & 15, lg = lane >> 4;
#pragma unroll
  for (int mi = 0; mi < 4; ++mi)
#pragma unroll
    for (int ni = 0; ni < 4; ++ni)
#pragma unroll
      for (int j = 0; j < 4; ++j) {
        int m = m0 + wm * 64 + mi * 16 + lg * 4 + j;
        int n = n0 + wn * 64 + ni * 16 + lr;
        out[(size_t)m * DD + n] = acc[mi][ni][j];
      }
}

extern "C" void kernel_launch(void* const* d_in, const int* in_sizes, int n_in,
                              void* d_out, int out_size, void* d_ws, size_t ws_size,
                              hipStream_t stream) {
  const float* x  = (const float*)d_in[0];
  const float* wq = (const float*)d_in[1];
  const float* wk = (const float*)d_in[2];
  const float* wv = (const float*)d_in[3];
  const float* wo = (const float*)d_in[4];
  const float* fc = (const float*)d_in[5];
  const float* fs = (const float*)d_in[6];
  float* out = (float*)d_out;

  char* ws = (char*)d_ws;
  u16* xb = (u16*)(ws);                      // 8 MB  : x as bf16 [4096][1024]
  u16* wT = (u16*)(ws + (8ull << 20));       // 8 MB  : wq,wk,wv,wo transposed bf16 [N][K]
  u16* Qr = (u16*)(ws + (16ull << 20));      // 8 MB  : Q roped  [b,h,s,hd]
  u16* Kr = (u16*)(ws + (24ull << 20));      // 8 MB  : K roped  [b,h,s,hd]
  u16* Vt = (u16*)(ws + (32ull << 20));      // 8 MB  : V transposed [b,h,hd,s]
  u16* Ob = (u16*)(ws + (40ull << 20));      // 8 MB  : attention output bf16 [4096][1024]

  cvt_x<<<4096, 256, 0, stream>>>(x, xb, 4096 * 1024);
  transpose_w<<<dim3(32, 32, 4), dim3(32, 8), 0, stream>>>(wq, wk, wv, wo, wT);
  gemm_qkv<<<dim3(32, 8, 3), 256, 0, stream>>>(xb, wT, fc, fs, Qr, Kr, Vt);
  attn<<<512, 256, 0, stream>>>(Qr, Kr, Vt, Ob);
  gemm_wo<<<dim3(32, 8), 256, 0, stream>>>(Ob, wT + 3ull * DD * DD, out);
}

// Round 4
// 202.071 us; speedup vs baseline: 1.4746x; 1.4746x over previous
//
#include <hip/hip_runtime.h>

typedef unsigned short u16;
typedef __bf16 bf16x8 __attribute__((ext_vector_type(8)));
typedef float f32x4 __attribute__((ext_vector_type(4)));

#define DD 1024
#define SS 2048
#define HH 16
#define HDIM 64

__device__ __forceinline__ u16 f2bf(float f) {
  union { float f; unsigned u; } x; x.f = f;
  unsigned r = x.u + 0x7FFFu + ((x.u >> 16) & 1u);
  return (u16)(r >> 16);
}

__device__ __forceinline__ void gload_lds16(const u16* g, u16* l) {
  __builtin_amdgcn_global_load_lds((const __attribute__((address_space(1))) void*)g,
                                   (__attribute__((address_space(3))) void*)l, 16, 0, 0);
}

// ---------------- fp32 -> bf16 convert ----------------
__global__ __launch_bounds__(256) void cvt_x(const float* __restrict__ in, u16* __restrict__ out, int n) {
  int i = (blockIdx.x * 256 + threadIdx.x) * 4;
  if (i + 3 < n) {
    float4 v = *(const float4*)(in + i);
    out[i + 0] = f2bf(v.x);
    out[i + 1] = f2bf(v.y);
    out[i + 2] = f2bf(v.z);
    out[i + 3] = f2bf(v.w);
  }
}

// ---------------- weight transpose + convert: out[n][k] = w[k][n] ----------------
__global__ __launch_bounds__(256) void transpose_w(const float* __restrict__ w0, const float* __restrict__ w1,
                                                   const float* __restrict__ w2, const float* __restrict__ w3,
                                                   u16* __restrict__ out) {
  __shared__ float t[32][33];
  const float* w = (blockIdx.z == 0) ? w0 : (blockIdx.z == 1) ? w1 : (blockIdx.z == 2) ? w2 : w3;
  u16* o = out + (size_t)blockIdx.z * DD * DD;
  int j0 = blockIdx.x * 32;  // n
  int i0 = blockIdx.y * 32;  // k
  int tx = threadIdx.x, ty = threadIdx.y;
#pragma unroll
  for (int r = ty; r < 32; r += 8)
    t[r][tx] = w[(size_t)(i0 + r) * DD + j0 + tx];
  __syncthreads();
#pragma unroll
  for (int r = ty; r < 32; r += 8)
    o[(size_t)(j0 + r) * DD + i0 + tx] = f2bf(t[tx][r]);
}

// ---------------- shared 128x128 GEMM core (A[M][K] bf16, BT[N][K] bf16) ----------------
__device__ __forceinline__ void gemm_128(const u16* __restrict__ A, const u16* __restrict__ BT,
                                         int m0, int n0, int K, u16* As, u16* Bs, f32x4 acc[4][4]) {
  const int tid = threadIdx.x;
  const int lane = tid & 63;
  const int wid = tid >> 6;
  const int wm = wid >> 1, wn = wid & 1;
  const int lr = lane & 15;
  const int lg = lane >> 4;
#pragma unroll
  for (int i = 0; i < 4; ++i)
#pragma unroll
    for (int j = 0; j < 4; ++j)
      acc[i][j] = (f32x4){0.f, 0.f, 0.f, 0.f};

  for (int kt = 0; kt < K / 64; ++kt) {
    int k0 = kt * 64;
    __syncthreads();
#pragma unroll
    for (int i = 0; i < 4; ++i) {
      int c = i * 256 + tid;
      int row = c >> 3;
      int j = (c & 7) ^ (row & 7);
      gload_lds16(A + (size_t)(m0 + row) * K + k0 + j * 8, As + c * 8);
      gload_lds16(BT + (size_t)(n0 + row) * K + k0 + j * 8, Bs + c * 8);
    }
    __syncthreads();
#pragma unroll
    for (int ks = 0; ks < 2; ++ks) {
      bf16x8 af[4], bfr[4];
#pragma unroll
      for (int mi = 0; mi < 4; ++mi) {
        int row = wm * 64 + mi * 16 + lr;
        int ch = (ks * 4 + lg) ^ (row & 7);
        af[mi] = *(const bf16x8*)(As + row * 64 + ch * 8);
      }
#pragma unroll
      for (int ni = 0; ni < 4; ++ni) {
        int row = wn * 64 + ni * 16 + lr;
        int ch = (ks * 4 + lg) ^ (row & 7);
        bfr[ni] = *(const bf16x8*)(Bs + row * 64 + ch * 8);
      }
      __builtin_amdgcn_s_setprio(1);
#pragma unroll
      for (int mi = 0; mi < 4; ++mi)
#pragma unroll
        for (int ni = 0; ni < 4; ++ni)
          acc[mi][ni] = __builtin_amdgcn_mfma_f32_16x16x32_bf16(af[mi], bfr[ni], acc[mi][ni], 0, 0, 0);
      __builtin_amdgcn_s_setprio(0);
    }
  }
}

// ---------------- QKV projection + RoPE epilogue ----------------
__global__ __launch_bounds__(256, 2) void gemm_qkv(const u16* __restrict__ xb, const u16* __restrict__ wT,
                                                   const float* __restrict__ fc, const float* __restrict__ fs,
                                                   u16* __restrict__ Qr, u16* __restrict__ Kr, u16* __restrict__ Vt) {
  __shared__ u16 As[128 * 64], Bs[128 * 64];
  const int z = blockIdx.z;
  const u16* BT = wT + (size_t)z * DD * DD;
  f32x4 acc[4][4];
  int m0 = blockIdx.x * 128, n0 = blockIdx.y * 128;
  gemm_128(xb, BT, m0, n0, DD, As, Bs, acc);

  const int lane = threadIdx.x & 63, wid = threadIdx.x >> 6;
  const int wm = wid >> 1, wn = wid & 1, lr = lane & 15, lg = lane >> 4;
#pragma unroll
  for (int mi = 0; mi < 4; ++mi)
#pragma unroll
    for (int ni = 0; ni < 4; ++ni)
#pragma unroll
      for (int j = 0; j < 4; ++j) {
        int m = m0 + wm * 64 + mi * 16 + lg * 4 + j;
        int n = n0 + wn * 64 + ni * 16 + lr;
        float v = acc[mi][ni][j];
        int b = m >> 11, s = m & 2047;
        int h = n >> 6, hd = n & 63;
        if (z == 2) {
          Vt[((size_t)(b * HH + h) * HDIM + hd) * SS + s] = f2bf(v);
        } else {
          float pv = __shfl_xor(v, 1);
          int fi = s * 32 + (hd >> 1);
          float c = fc[fi], sn = fs[fi];
          float o = ((hd & 1) == 0) ? (v * c - pv * sn) : (pv * sn + v * c);
          u16* dst = (z == 0) ? Qr : Kr;
          dst[((size_t)(b * HH + h) * SS + s) * HDIM + hd] = f2bf(o);
        }
      }
}

// ---------------- flash attention (causal), one 64-row q-tile pass, KVBLK=64 ----------------
__device__ __forceinline__ void attn_pass(int qt, int bh, const u16* __restrict__ Qh,
                                          const u16* __restrict__ Kh, const u16* __restrict__ Vh,
                                          u16* __restrict__ Ob, u16* __restrict__ Pw) {
  const int lane = threadIdx.x & 63, wid = threadIdx.x >> 6;
  const int lr = lane & 15, lg = lane >> 4;
  const int q0 = qt * 64 + wid * 16;

  bf16x8 aq[2];
#pragma unroll
  for (int ks = 0; ks < 2; ++ks)
    aq[ks] = *(const bf16x8*)(Qh + (q0 + lr) * HDIM + ks * 32 + lg * 8);

  // all-ones B fragment: row-sum of P via MFMA (replaces psum shuffle reduce)
  bf16x8 ones;
  {
    union { u16 u[8]; bf16x8 v; } ou;
#pragma unroll
    for (int i = 0; i < 8; ++i) ou.u[i] = 0x3F80;
    ones = ou.v;
  }

  f32x4 o[4];
#pragma unroll
  for (int d = 0; d < 4; ++d) o[d] = (f32x4){0.f, 0.f, 0.f, 0.f};
  f32x4 ls = (f32x4){0.f, 0.f, 0.f, 0.f};  // softmax denominator accumulator
  float mrun[4];
#pragma unroll
  for (int j = 0; j < 4; ++j) mrun[j] = -1e30f;

  // preload K fragments for t=0
  bf16x8 kf[2][4];
#pragma unroll
  for (int ks = 0; ks < 2; ++ks)
#pragma unroll
    for (int kb = 0; kb < 4; ++kb)
      kf[ks][kb] = *(const bf16x8*)(Kh + (kb * 16 + lr) * HDIM + ks * 32 + lg * 8);

  for (int t = 0; t <= qt; ++t) {
    // V fragments for this tile: issue FIRST (latency hides under QK^T + softmax)
    bf16x8 vf[2][4];
#pragma unroll
    for (int ks = 0; ks < 2; ++ks)
#pragma unroll
      for (int d = 0; d < 4; ++d)
        vf[ks][d] = *(const bf16x8*)(Vh + (d * 16 + lr) * SS + t * 64 + ks * 32 + lg * 8);

    f32x4 sc[4];
#pragma unroll
    for (int kb = 0; kb < 4; ++kb) sc[kb] = (f32x4){0.f, 0.f, 0.f, 0.f};
    __builtin_amdgcn_s_setprio(1);
#pragma unroll
    for (int ks = 0; ks < 2; ++ks)
#pragma unroll
      for (int kb = 0; kb < 4; ++kb)
        sc[kb] = __builtin_amdgcn_mfma_f32_16x16x32_bf16(aq[ks], kf[ks][kb], sc[kb], 0, 0, 0);
    __builtin_amdgcn_s_setprio(0);

    // prefetch next K tile (clamped; latency hides under softmax + PV)
    const int tn = (t < qt) ? (t + 1) : qt;
    bf16x8 kn[2][4];
#pragma unroll
    for (int ks = 0; ks < 2; ++ks)
#pragma unroll
      for (int kb = 0; kb < 4; ++kb)
        kn[ks][kb] = *(const bf16x8*)(Kh + (tn * 64 + kb * 16 + lr) * HDIM + ks * 32 + lg * 8);

    // scale + causal mask (diagonal tile only); rows q = q0 + lg*4 + j, col kk = t*64 + kb*16 + lr
    float p[4][4];
    float pm[4] = {-1e30f, -1e30f, -1e30f, -1e30f};
    if (t == qt) {
#pragma unroll
      for (int kb = 0; kb < 4; ++kb)
#pragma unroll
        for (int j = 0; j < 4; ++j) {
          int q = q0 + lg * 4 + j;
          int kk = t * 64 + kb * 16 + lr;
          float v = sc[kb][j] * 0.125f;
          if (kk > q) v = -1e30f;
          p[kb][j] = v;
          pm[j] = fmaxf(pm[j], v);
        }
    } else {
#pragma unroll
      for (int kb = 0; kb < 4; ++kb)
#pragma unroll
        for (int j = 0; j < 4; ++j) {
          float v = sc[kb][j] * 0.125f;
          p[kb][j] = v;
          pm[j] = fmaxf(pm[j], v);
        }
    }
#pragma unroll
    for (int d = 1; d < 16; d <<= 1)
#pragma unroll
      for (int j = 0; j < 4; ++j) pm[j] = fmaxf(pm[j], __shfl_xor(pm[j], d));
    float alpha[4];
#pragma unroll
    for (int j = 0; j < 4; ++j) {
      float mn = fmaxf(mrun[j], pm[j]);
      alpha[j] = __expf(mrun[j] - mn);
      mrun[j] = mn;
    }
#pragma unroll
    for (int kb = 0; kb < 4; ++kb)
#pragma unroll
      for (int j = 0; j < 4; ++j)
        p[kb][j] = __expf(p[kb][j] - mrun[j]);
#pragma unroll
    for (int j = 0; j < 4; ++j) ls[j] *= alpha[j];
#pragma unroll
    for (int d = 0; d < 4; ++d)
#pragma unroll
      for (int j = 0; j < 4; ++j) o[d][j] *= alpha[j];
    // P -> per-wave LDS (swizzled), then PV (+ row-sum via ones-MFMA)
#pragma unroll
    for (int kb = 0; kb < 4; ++kb)
#pragma unroll
      for (int j = 0; j < 4; ++j) {
        int r = lg * 4 + j;
        int ccol = kb * 16 + lr;
        int ch = (ccol >> 3) ^ (r & 7);
        Pw[r * 64 + ch * 8 + (ccol & 7)] = f2bf(p[kb][j]);
      }
#pragma unroll
    for (int ks = 0; ks < 2; ++ks) {
      int ch = (ks * 4 + lg) ^ (lr & 7);
      bf16x8 ap = *(const bf16x8*)(Pw + lr * 64 + ch * 8);
      __builtin_amdgcn_s_setprio(1);
      ls = __builtin_amdgcn_mfma_f32_16x16x32_bf16(ap, ones, ls, 0, 0, 0);
#pragma unroll
      for (int d = 0; d < 4; ++d)
        o[d] = __builtin_amdgcn_mfma_f32_16x16x32_bf16(ap, vf[ks][d], o[d], 0, 0, 0);
      __builtin_amdgcn_s_setprio(0);
    }
#pragma unroll
    for (int ks = 0; ks < 2; ++ks)
#pragma unroll
      for (int kb = 0; kb < 4; ++kb)
        kf[ks][kb] = kn[ks][kb];
  }
  const int b = bh >> 4, h = bh & 15;
#pragma unroll
  for (int d = 0; d < 4; ++d)
#pragma unroll
    for (int j = 0; j < 4; ++j) {
      int s = q0 + lg * 4 + j;
      int col = h * HDIM + d * 16 + lr;
      Ob[((size_t)b * SS + s) * DD + col] = f2bf(o[d][j] / ls[j]);
    }
}

// 512 flat blocks; XCD-aware mapping: xcd = id&7 owns heads 4*xcd..4*xcd+3 (K/V L2-resident).
// Block processes q-tiles {pair, 31-pair} -> 34 K-iters for every block (balanced).
__global__ __launch_bounds__(256, 2) void attn(const u16* __restrict__ Qr, const u16* __restrict__ Kr,
                                               const u16* __restrict__ Vt, u16* __restrict__ Ob) {
  __shared__ u16 Ps[4][16 * 64];
  const int id = blockIdx.x;
  const int xcd = id & 7;
  const int idx = id >> 3;
  const int pair = idx & 15;
  const int bh = xcd * 4 + (idx >> 4);
  const u16* Qh = Qr + (size_t)bh * SS * HDIM;
  const u16* Kh = Kr + (size_t)bh * SS * HDIM;
  const u16* Vh = Vt + (size_t)bh * HDIM * SS;
  u16* Pw = &Ps[threadIdx.x >> 6][0];
  attn_pass(pair, bh, Qh, Kh, Vh, Ob, Pw);
  attn_pass(31 - pair, bh, Qh, Kh, Vh, Ob, Pw);
}

// ---------------- output projection: fp32 out ----------------
__global__ __launch_bounds__(256, 2) void gemm_wo(const u16* __restrict__ Ab, const u16* __restrict__ woT,
                                                  float* __restrict__ out) {
  __shared__ u16 As[128 * 64], Bs[128 * 64];
  f32x4 acc[4][4];
  int m0 = blockIdx.x * 128, n0 = blockIdx.y * 128;
  gemm_128(Ab, woT, m0, n0, DD, As, Bs, acc);
  const int lane = threadIdx.x & 63, wid = threadIdx.x >> 6;
  const int wm = wid >> 1, wn = wid & 1, lr = lane & 15, lg = lane >> 4;
#pragma unroll
  for (int mi = 0; mi < 4; ++mi)
#pragma unroll
    for (int ni = 0; ni < 4; ++ni)
#pragma unroll
      for (int j = 0; j < 4; ++j) {
        int m = m0 + wm * 64 + mi * 16 + lg * 4 + j;
        int n = n0 + wn * 64 + ni * 16 + lr;
        out[(size_t)m * DD + n] = acc[mi][ni][j];
      }
}

extern "C" void kernel_launch(void* const* d_in, const int* in_sizes, int n_in,
                              void* d_out, int out_size, void* d_ws, size_t ws_size,
                              hipStream_t stream) {
  const float* x  = (const float*)d_in[0];
  const float* wq = (const float*)d_in[1];
  const float* wk = (const float*)d_in[2];
  const float* wv = (const float*)d_in[3];
  const float* wo = (const float*)d_in[4];
  const float* fc = (const float*)d_in[5];
  const float* fs = (const float*)d_in[6];
  float* out = (float*)d_out;

  char* ws = (char*)d_ws;
  u16* xb = (u16*)(ws);                      // 8 MB  : x as bf16 [4096][1024]
  u16* wT = (u16*)(ws + (8ull << 20));       // 8 MB  : wq,wk,wv,wo transposed bf16 [N][K]
  u16* Qr = (u16*)(ws + (16ull << 20));      // 8 MB  : Q roped  [b,h,s,hd]
  u16* Kr = (u16*)(ws + (24ull << 20));      // 8 MB  : K roped  [b,h,s,hd]
  u16* Vt = (u16*)(ws + (32ull << 20));      // 8 MB  : V transposed [b,h,hd,s]
  u16* Ob = (u16*)(ws + (40ull << 20));      // 8 MB  : attention output bf16 [4096][1024]

  cvt_x<<<4096, 256, 0, stream>>>(x, xb, 4096 * 1024);
  transpose_w<<<dim3(32, 32, 4), dim3(32, 8), 0, stream>>>(wq, wk, wv, wo, wT);
  gemm_qkv<<<dim3(32, 8, 3), 256, 0, stream>>>(xb, wT, fc, fs, Qr, Kr, Vt);
  attn<<<512, 256, 0, stream>>>(Qr, Kr, Vt, Ob);
  gemm_wo<<<dim3(32, 8), 256, 0, stream>>>(Ob, wT + 3ull * DD * DD, out);
}